// Round 9
// baseline (946.485 us; speedup 1.0000x reference)
//
#include <hip/hip_runtime.h>
#include <math.h>
#include <stdint.h>

#define SEQ 2048
#define DMODEL 512
#define NH 8
#define DHEAD 64
#define NL 4
#define DFF 2048

typedef __attribute__((ext_vector_type(8))) short short8;
typedef __attribute__((ext_vector_type(4))) float f32x4;

__device__ __forceinline__ short f2bf(float f) {
  unsigned u = __float_as_uint(f);
  u += 0x7fffu + ((u >> 16) & 1u);
  return (short)(u >> 16);
}
__device__ __forceinline__ float silu_f(float x) { return x / (1.f + __expf(-x)); }

// async global->LDS, 16B per lane; HW dest = wave-uniform base + lane*16
__device__ __forceinline__ void cp16(const void* g, void* l) {
  __builtin_amdgcn_global_load_lds(
      (const __attribute__((address_space(1))) unsigned*)(unsigned long long)(uintptr_t)g,
      (__attribute__((address_space(3))) unsigned*)(unsigned)(uintptr_t)l, 16, 0, 0);
}

// ---------------- merged prep: 7 transposes + sincos tables + counter zeroing ----------------
struct TP { const float* src; short* dst; int rows, cols, base, lstride; };
struct TPs { TP t[7]; };
__global__ __launch_bounds__(256) void k_prep(TPs ts, float* __restrict__ sn, float* __restrict__ cs,
                                              int* __restrict__ cnt) {
  int bid = blockIdx.x;
  if (bid >= 13312) { // 256 blocks: fp64 sincos (65536 entries) + cnt zero
    int g = (bid - 13312) * 256 + threadIdx.x;
    if (bid == 13312) {
#pragma unroll
      for (int j = 0; j < 4; ++j) cnt[threadIdx.x * 4 + j] = 0; // NL*256 = 1024 ints
    }
    int s = g >> 5, p = g & 31;
    double inv = pow(10000.0, -(double)p / 32.0);
    double a = (double)s * inv;
    float sv = (float)sin(a), cv = (float)cos(a);
    sn[s * DHEAD + 2 * p] = sv; sn[s * DHEAD + 2 * p + 1] = sv;
    cs[s * DHEAD + 2 * p] = cv; cs[s * DHEAD + 2 * p + 1] = cv;
    return;
  }
  int di = 6;
  while (di > 0 && bid < ts.t[di].base) --di;
  TP d = ts.t[di];
  int local = bid - d.base;
  int tx = d.cols >> 5, ty = d.rows >> 5;
  int tpz = tx * ty;
  int z = local / tpz, rem = local - z * tpz;
  int bx = (rem % tx) * 32, by = (rem / tx) * 32;
  const float* src = d.src + (size_t)z * d.rows * d.cols;
  short* dst = d.dst + (size_t)z * d.lstride;
  __shared__ float tile[32][33];
  int txi = threadIdx.x & 31, tyi = threadIdx.x >> 5; // 32 x 8
#pragma unroll
  for (int k = 0; k < 4; ++k)
    tile[tyi + k * 8][txi] = src[(size_t)(by + tyi + k * 8) * d.cols + bx + txi];
  __syncthreads();
#pragma unroll
  for (int k = 0; k < 4; ++k)
    dst[(size_t)(bx + tyi + k * 8) * d.rows + by + txi] = f2bf(tile[txi][tyi + k * 8]);
}

// ---------------- LayerNorm row(512): xnew = x + pos?(row0) + sum(parts); write-back; LN->bf16 ----------------
__global__ __launch_bounds__(256) void k_ln(const float* __restrict__ x, const float* __restrict__ parts, int np,
                                            const float* __restrict__ w, const float* __restrict__ b,
                                            short* __restrict__ o, float eps, float* __restrict__ xout,
                                            const float* __restrict__ pos) {
  int wid = threadIdx.x >> 6, lane = threadIdx.x & 63;
  int row = blockIdx.x * 4 + wid;
  size_t base = (size_t)row * DMODEL + lane * 8;
  float4 v0 = *(const float4*)(x + base);
  float4 v1 = *(const float4*)(x + base + 4);
  if (pos) { // reference broadcasts pos_emb[:B] => row 0 only
    float4 p0 = *(const float4*)(pos + lane * 8);
    float4 p1 = *(const float4*)(pos + lane * 8 + 4);
    v0.x += p0.x; v0.y += p0.y; v0.z += p0.z; v0.w += p0.w;
    v1.x += p1.x; v1.y += p1.y; v1.z += p1.z; v1.w += p1.w;
  }
  for (int p = 0; p < np; ++p) {
    const float* pp = parts + (size_t)p * SEQ * DMODEL;
    float4 a0 = *(const float4*)(pp + base);
    float4 a1 = *(const float4*)(pp + base + 4);
    v0.x += a0.x; v0.y += a0.y; v0.z += a0.z; v0.w += a0.w;
    v1.x += a1.x; v1.y += a1.y; v1.z += a1.z; v1.w += a1.w;
  }
  if (xout) {
    *(float4*)(xout + base) = v0;
    *(float4*)(xout + base + 4) = v1;
  }
  float sm = v0.x + v0.y + v0.z + v0.w + v1.x + v1.y + v1.z + v1.w;
  float sq = v0.x * v0.x + v0.y * v0.y + v0.z * v0.z + v0.w * v0.w +
             v1.x * v1.x + v1.y * v1.y + v1.z * v1.z + v1.w * v1.w;
#pragma unroll
  for (int m = 1; m < 64; m <<= 1) { sm += __shfl_xor(sm, m); sq += __shfl_xor(sq, m); }
  float mu = sm * (1.f / 512.f);
  float rstd = rsqrtf(sq * (1.f / 512.f) - mu * mu + eps);
  const float* wr = w + lane * 8; const float* br = b + lane * 8;
  float vals[8] = {v0.x, v0.y, v0.z, v0.w, v1.x, v1.y, v1.z, v1.w};
  short t[8] __attribute__((aligned(16)));
#pragma unroll
  for (int i = 0; i < 8; ++i) t[i] = f2bf((vals[i] - mu) * rstd * wr[i] + br[i]);
  *(int4*)(o + (size_t)row * DMODEL + lane * 8) = *(int4*)t;
}

// ---------------- bf16 MFMA GEMM, 64xBN tile, dbuf LDS via cp16, XOR-swizzled ----------------
// EPI: 0 fp32 store (DMODEL stride) | 1 silu->bf16 (N stride) | 2 fp32 PARTIAL at out+z*M*DMODEL (bias z==0)
//      4 bf16 transposed out[col*M+row] | 5 rope-q (*0.125)->bf16 | 6 rope-k ->bf16
// wide=1: N covers 4 slices of 512 cols; gb = b[n0>>9]; colO = col & 511.
struct GB { const short* Bt; const float* bias; void* out; int mode; };
struct GP {
  const short* A;
  const float* sn; const float* cs;
  GB b[4];
  int M, N, K, kspl, wide;
};

template <int BN>
__global__ __launch_bounds__(256) void k_gemm(GP ga) {
  constexpr int NBW = BN / 32;     // b-frags per wave (waves 2m x 2n)
  constexpr int BRND = BN / 32;    // cp16 rounds for B tile
  const int z = blockIdx.z;
  const int n0 = blockIdx.x * BN, m0 = blockIdx.y * 64;
  GB gb; int k0, klen;
  if (ga.kspl > 0) { gb = ga.b[0]; k0 = z * ga.kspl; klen = ga.kspl; }
  else { gb = ga.wide ? ga.b[n0 >> 9] : ga.b[z]; k0 = 0; klen = ga.K; }
  const int K = ga.K, N = ga.N, M = ga.M;
  const int tid = threadIdx.x;
  const int w = tid >> 6, lane = tid & 63, l16 = lane & 15, quad = lane >> 4;
  const int wm = (w & 1) * 32, wn = (w >> 1) * (BN / 2);
  const int nIter = klen >> 6;

  __shared__ __align__(16) short As[2][4096];      // [64][64] unpadded, chunk ^= (row&7)
  __shared__ __align__(16) short Bs[2][BN * 64];

  const short* Ab = ga.A + (size_t)m0 * K + k0;
  const short* Bb = gb.Bt + (size_t)n0 * K + k0;
  const int rsub = lane >> 3, cch = (lane & 7) ^ rsub;

  auto stage = [&](int buf, int it) {
#pragma unroll
    for (int c = 0; c < 2; ++c) {
      int seg = w + 4 * c;
      cp16(Ab + (size_t)(seg * 8 + rsub) * K + (it << 6) + cch * 8, &As[buf][seg * 512]);
    }
#pragma unroll
    for (int c = 0; c < BRND; ++c) {
      int seg = w + 4 * c;
      cp16(Bb + (size_t)(seg * 8 + rsub) * K + (it << 6) + cch * 8, &Bs[buf][seg * 512]);
    }
  };

  f32x4 acc[2][NBW];
#pragma unroll
  for (int a = 0; a < 2; ++a)
#pragma unroll
    for (int b = 0; b < NBW; ++b) acc[a][b] = {0.f, 0.f, 0.f, 0.f};

  stage(0, 0);
  for (int it = 0; it < nIter; ++it) {
    __syncthreads(); // vmcnt(0) drain: buf[it&1] ready
    if (it + 1 < nIter) stage((it + 1) & 1, it + 1);
    const short* as = As[it & 1];
    const short* bs = Bs[it & 1];
#pragma unroll
    for (int kki = 0; kki < 2; ++kki) {
      int ch = ((quad + 4 * kki) ^ (l16 & 7)) * 8;
      short8 af[2], bfv[NBW];
#pragma unroll
      for (int a = 0; a < 2; ++a) af[a] = *(const short8*)&as[(wm + a * 16 + l16) * 64 + ch];
#pragma unroll
      for (int b = 0; b < NBW; ++b) bfv[b] = *(const short8*)&bs[(wn + b * 16 + l16) * 64 + ch];
#pragma unroll
      for (int a = 0; a < 2; ++a)
#pragma unroll
        for (int b = 0; b < NBW; ++b)
          acc[a][b] = __builtin_amdgcn_mfma_f32_16x16x32_bf16(af[a], bfv[b], acc[a][b], 0, 0, 0);
    }
  }

  // epilogue: C/D layout col=lane&15, row=quad*4+reg (m89-verified)
  const int mode = gb.mode;
#pragma unroll
  for (int a = 0; a < 2; ++a) {
#pragma unroll
    for (int b = 0; b < NBW; ++b) {
      int row0 = m0 + wm + a * 16 + quad * 4;
      int col = n0 + wn + b * 16 + l16;
      int colO = ga.wide ? (col & 511) : col;
      float bi = (mode == 2 && z > 0) ? 0.f : gb.bias[colO];
      float vals[4];
#pragma unroll
      for (int r = 0; r < 4; ++r) vals[r] = acc[a][b][r] + bi;
      if (mode == 5 || mode == 6) {
        float sc = (mode == 5) ? 0.125f : 1.f;
        int d = colO & 63;
#pragma unroll
        for (int r = 0; r < 4; ++r) {
          int s = row0 + r;
          float vv = vals[r];
          float p = __shfl_xor(vv, 1); // partner col^1 lives in lane^1
          float rot = (colO & 1) ? p : -p;
          float o = (vv * ga.cs[s * 64 + d] + rot * ga.sn[s * 64 + d]) * sc;
          ((short*)gb.out)[(size_t)s * DMODEL + colO] = f2bf(o);
        }
      } else if (mode == 4) {
        short t4[4] __attribute__((aligned(8)));
#pragma unroll
        for (int r = 0; r < 4; ++r) t4[r] = f2bf(vals[r]);
        *(uint2*)&((short*)gb.out)[(size_t)colO * M + row0] = *(const uint2*)t4;
      } else if (mode == 0) {
#pragma unroll
        for (int r = 0; r < 4; ++r) ((float*)gb.out)[(size_t)(row0 + r) * DMODEL + colO] = vals[r];
      } else if (mode == 1) {
#pragma unroll
        for (int r = 0; r < 4; ++r) ((short*)gb.out)[(size_t)(row0 + r) * N + col] = f2bf(silu_f(vals[r]));
      } else { // mode 2: deterministic K-split partial
        float* po = (float*)gb.out + (size_t)z * M * DMODEL;
#pragma unroll
        for (int r = 0; r < 4; ++r) po[(size_t)(row0 + r) * DMODEL + colO] = vals[r];
      }
    }
  }
}

// ---------------- retention via MFMA, j-parity split, fused second-finisher retgate ----------------
__global__ __launch_bounds__(256) void k_attn(const short* __restrict__ qb, const short* __restrict__ kb,
                                              const short* __restrict__ vtb, float* __restrict__ r0,
                                              float* __restrict__ r1, const float* __restrict__ graw,
                                              short* __restrict__ grb, int* __restrict__ cnt) {
  int x = blockIdx.x, hd = blockIdx.y, jc = blockIdx.z;
  int ib = jc ? (31 - x) : x; // balance: co-resident (x,0)+(x,1) ~ constant work
  int t = threadIdx.x;
  int w = t >> 6, lane = t & 63, l16 = lane & 15, quad = lane >> 4;
  __shared__ __align__(16) short smem[4 * 64 * 72];
  __shared__ int second;
  short* qs = smem;
  short* kt = smem + 4608;
  short* vt = smem + 9216;
  short* p  = smem + 13824;

  double stepd = (log(1.0 / 512.0) - log(1.0 / 32.0)) / 7.0;
  double gam = 1.0 - exp(log(1.0 / 32.0) + hd * stepd);
  float l2g = (float)(log(gam) * 1.4426950408889634);

  for (int c = t; c < 512; c += 256) {
    int r = c >> 3, d8 = (c & 7) * 8;
    *(short8*)&qs[r * 72 + d8] = *(const short8*)&qb[(size_t)(ib * 64 + r) * DMODEL + hd * DHEAD + d8];
  }
  f32x4 oacc[4];
#pragma unroll
  for (int b = 0; b < 4; ++b) oacc[b] = {0.f, 0.f, 0.f, 0.f};

  for (int jb = jc; jb <= ib; jb += 2) {
    __syncthreads();
    for (int c = t; c < 512; c += 256) {
      int r = c >> 3, d8 = (c & 7) * 8;
      *(short8*)&kt[r * 72 + d8] = *(const short8*)&kb[(size_t)(jb * 64 + r) * DMODEL + hd * DHEAD + d8];
      *(short8*)&vt[r * 72 + d8] = *(const short8*)&vtb[(size_t)(hd * DHEAD + r) * SEQ + jb * 64 + d8];
    }
    __syncthreads();
    f32x4 sacc[4];
#pragma unroll
    for (int b = 0; b < 4; ++b) sacc[b] = {0.f, 0.f, 0.f, 0.f};
#pragma unroll
    for (int kk = 0; kk < 64; kk += 32) {
      short8 af = *(const short8*)&qs[(w * 16 + l16) * 72 + kk + quad * 8];
#pragma unroll
      for (int b = 0; b < 4; ++b) {
        short8 bf_ = *(const short8*)&kt[(b * 16 + l16) * 72 + kk + quad * 8];
        sacc[b] = __builtin_amdgcn_mfma_f32_16x16x32_bf16(af, bf_, sacc[b], 0, 0, 0);
      }
    }
    int dtile = (ib - jb) * 64;
#pragma unroll
    for (int b = 0; b < 4; ++b) {
#pragma unroll
      for (int r = 0; r < 4; ++r) {
        int iloc = w * 16 + quad * 4 + r;
        int jloc = b * 16 + l16;
        int df = dtile + iloc - jloc;
        float dec = (df < 0) ? 0.f : exp2f(l2g * (float)df);
        p[iloc * 72 + jloc] = f2bf(sacc[b][r] * dec);
      }
    }
    __syncthreads();
#pragma unroll
    for (int kk = 0; kk < 64; kk += 32) {
      short8 af = *(const short8*)&vt[(w * 16 + l16) * 72 + kk + quad * 8];
#pragma unroll
      for (int b = 0; b < 4; ++b) {
        short8 bf_ = *(const short8*)&p[(b * 16 + l16) * 72 + kk + quad * 8];
        oacc[b] = __builtin_amdgcn_mfma_f32_16x16x32_bf16(af, bf_, oacc[b], 0, 0, 0);
      }
    }
  }
  __syncthreads();
  float* obuf = (float*)smem; // [64][68] fp32
#pragma unroll
  for (int b = 0; b < 4; ++b) {
#pragma unroll
    for (int r = 0; r < 4; ++r) {
      int d = w * 16 + quad * 4 + r;
      int i = b * 16 + l16;
      obuf[i * 68 + d] = oacc[b][r];
    }
  }
  __syncthreads();
  float* rp = jc ? r1 : r0;
  for (int c = t; c < 1024; c += 256) {
    int r = c >> 4, d4 = (c & 15) * 4;
    *(float4*)&rp[(size_t)(ib * 64 + r) * DMODEL + hd * DHEAD + d4] = *(const float4*)&obuf[r * 68 + d4];
  }
  // second-finisher retgate: the later of the two parity blocks combines + normalizes + gates
  __threadfence(); // release: partial visible before counter bump
  if (t == 0) second = atomicAdd(&cnt[ib * 8 + hd], 1);
  __syncthreads();
  if (second == 1) {
    __threadfence(); // acquire: partner's partial visible
    const float* other = jc ? r0 : r1;
    for (int k = 0; k < 16; ++k) {
      int r = w * 16 + k;
      size_t gbase = (size_t)(ib * 64 + r) * DMODEL + hd * DHEAD + lane;
      float v = obuf[r * 68 + lane] + other[gbase];
      float sm = v, sq = v * v;
#pragma unroll
      for (int m = 1; m < 64; m <<= 1) { sm += __shfl_xor(sm, m); sq += __shfl_xor(sq, m); }
      float mu = sm * (1.f / 64.f);
      float var = sq * (1.f / 64.f) - mu * mu;
      float rn = (v - mu) * rsqrtf(var + 1e-6f);
      grb[gbase] = f2bf(silu_f(graw[gbase]) * rn);
    }
  }
}

// ---------------- out = sigmoid((x + sum parts) @ Wout + bout), one wave per row ----------------
__global__ __launch_bounds__(256) void k_final(const float* __restrict__ x, const float* __restrict__ parts, int np,
                                               const float* __restrict__ w, const float* __restrict__ bo,
                                               float* __restrict__ o) {
  int wid = threadIdx.x >> 6, lane = threadIdx.x & 63;
  int row = blockIdx.x * 4 + wid;
  size_t base = (size_t)row * DMODEL + lane * 8;
  float4 a0 = *(const float4*)(x + base), a1 = *(const float4*)(x + base + 4);
  for (int p = 0; p < np; ++p) {
    const float* pp = parts + (size_t)p * SEQ * DMODEL;
    float4 b0 = *(const float4*)(pp + base);
    float4 b1 = *(const float4*)(pp + base + 4);
    a0.x += b0.x; a0.y += b0.y; a0.z += b0.z; a0.w += b0.w;
    a1.x += b1.x; a1.y += b1.y; a1.z += b1.z; a1.w += b1.w;
  }
  float4 w0 = *(const float4*)(w + lane * 8), w1 = *(const float4*)(w + lane * 8 + 4);
  float sm = a0.x * w0.x + a0.y * w0.y + a0.z * w0.z + a0.w * w0.w +
             a1.x * w1.x + a1.y * w1.y + a1.z * w1.z + a1.w * w1.w;
#pragma unroll
  for (int m = 1; m < 64; m <<= 1) sm += __shfl_xor(sm, m);
  if (lane == 0) o[row] = 1.f / (1.f + __expf(-(sm + bo[0])));
}

extern "C" void kernel_launch(void* const* d_in, const int* in_sizes, int n_in,
                              void* d_out, int out_size, void* d_ws, size_t ws_size,
                              hipStream_t stream) {
  const float* x_in = (const float*)d_in[0];
  const float* pos = (const float*)d_in[1];
  const float* Wq = (const float*)d_in[2];  const float* bq = (const float*)d_in[3];
  const float* Wk = (const float*)d_in[4];  const float* bk = (const float*)d_in[5];
  const float* Wv = (const float*)d_in[6];  const float* bv = (const float*)d_in[7];
  const float* Wg = (const float*)d_in[8];  const float* bg = (const float*)d_in[9];
  const float* Wo = (const float*)d_in[10]; const float* bo = (const float*)d_in[11];
  const float* ln1w = (const float*)d_in[12]; const float* ln1b = (const float*)d_in[13];
  const float* ln2w = (const float*)d_in[14]; const float* ln2b = (const float*)d_in[15];
  const float* W1 = (const float*)d_in[16]; const float* b1 = (const float*)d_in[17];
  const float* W2 = (const float*)d_in[18]; const float* b2 = (const float*)d_in[19];
  const float* Wout = (const float*)d_in[20]; const float* bout = (const float*)d_in[21];
  float* out = (float*)d_out;

  char* ws = (char*)d_ws;
  size_t off = 0;
  auto alloc = [&](size_t bytes) -> void* {
    void* p = ws + off;
    off += (bytes + 255) & ~(size_t)255;
    return p;
  };
  const size_t DD = (size_t)DMODEL * DMODEL;
  const size_t SD = (size_t)SEQ * DMODEL;
  short* wqkvg = (short*)alloc((size_t)NL * 4 * DD * 2); // [l][slice q,k,v,g][n][k]
  short* wot = (short*)alloc((size_t)NL * DD * 2);
  short* w1t = (short*)alloc((size_t)NL * DMODEL * DFF * 2);
  short* w2t = (short*)alloc((size_t)NL * DMODEL * DFF * 2);
  float* xb = (float*)alloc(SD * 4);
  short* ybf = (short*)alloc(SD * 2);
  float* graw = (float*)alloc(SD * 4);
  short* qb = (short*)alloc(SD * 2);
  short* kb = (short*)alloc(SD * 2);
  short* vtb = (short*)alloc(SD * 2);
  float* ret0 = (float*)alloc(SD * 4);
  float* ret1 = (float*)alloc(SD * 4);
  short* grb = (short*)alloc(SD * 2);
  short* zbf = (short*)alloc(SD * 2);
  short* hbf = (short*)alloc((size_t)SEQ * DFF * 2);
  float* sint = (float*)alloc((size_t)SEQ * DHEAD * 4);
  float* cost = (float*)alloc((size_t)SEQ * DHEAD * 4);
  float* wpart = (float*)alloc(2 * SD * 4);  // Wo K-split partials
  float* fpart = (float*)alloc(4 * SD * 4);  // FFN2 K-split partials
  int* cnt = (int*)alloc(NL * 256 * 4);      // attn second-finisher counters

  TPs tp;
  tp.t[0] = TP{Wq, wqkvg + 0 * DD, DMODEL, DMODEL, 0, (int)(4 * DD)};
  tp.t[1] = TP{Wk, wqkvg + 1 * DD, DMODEL, DMODEL, 1024, (int)(4 * DD)};
  tp.t[2] = TP{Wv, wqkvg + 2 * DD, DMODEL, DMODEL, 2048, (int)(4 * DD)};
  tp.t[3] = TP{Wg, wqkvg + 3 * DD, DMODEL, DMODEL, 3072, (int)(4 * DD)};
  tp.t[4] = TP{Wo, wot, DMODEL, DMODEL, 4096, (int)DD};
  tp.t[5] = TP{W1, w1t, DMODEL, DFF, 5120, DMODEL * DFF};
  tp.t[6] = TP{W2, w2t, DFF, DMODEL, 9216, DMODEL * DFF};
  k_prep<<<13568, 256, 0, stream>>>(tp, sint, cost, cnt);

  for (int l = 0; l < NL; ++l) {
    // LN1: l==0 reads x_in + pos(row0), writes xb; l>0 reduces FFN2 partials into xb
    k_ln<<<SEQ / 4, 256, 0, stream>>>(l == 0 ? x_in : xb, fpart, l == 0 ? 0 : 4,
                                      ln1w + l * DMODEL, ln1b + l * DMODEL, ybf, 1e-5f,
                                      xb, l == 0 ? pos : nullptr);

    // merged qkvg: one GEMM, N=2048 (4 slices of 512), 512 blocks
    GP gq{};
    gq.A = ybf; gq.sn = sint; gq.cs = cost;
    gq.b[0] = GB{wqkvg + (size_t)l * 4 * DD, bq + l * DMODEL, qb, 5};
    gq.b[1] = GB{wqkvg + (size_t)l * 4 * DD, bk + l * DMODEL, kb, 6};
    gq.b[2] = GB{wqkvg + (size_t)l * 4 * DD, bv + l * DMODEL, vtb, 4};
    gq.b[3] = GB{wqkvg + (size_t)l * 4 * DD, bg + l * DMODEL, graw, 0};
    gq.M = SEQ; gq.N = 4 * DMODEL; gq.K = DMODEL; gq.kspl = 0; gq.wide = 1;
    k_gemm<128><<<dim3(16, SEQ / 64, 1), 256, 0, stream>>>(gq);

    k_attn<<<dim3(32, NH, 2), 256, 0, stream>>>(qb, kb, vtb, ret0, ret1, graw, grb, cnt + l * 256);

    GP gw{};
    gw.A = grb;
    gw.b[0] = GB{wot + l * DD, bo + l * DMODEL, wpart, 2};
    gw.M = SEQ; gw.N = DMODEL; gw.K = DMODEL; gw.kspl = 256; gw.wide = 0;
    k_gemm<64><<<dim3(DMODEL / 64, SEQ / 64, 2), 256, 0, stream>>>(gw);

    // LN2 + reduce of Wo partials into xb
    k_ln<<<SEQ / 4, 256, 0, stream>>>(xb, wpart, 2,
                                      ln2w + l * DMODEL, ln2b + l * DMODEL, zbf, 1e-5f, xb, nullptr);

    GP g1{};
    g1.A = zbf;
    g1.b[0] = GB{w1t + (size_t)l * DMODEL * DFF, b1 + l * DFF, hbf, 1};
    g1.M = SEQ; g1.N = DFF; g1.K = DMODEL; g1.kspl = 0; g1.wide = 0;
    k_gemm<128><<<dim3(DFF / 128, SEQ / 64, 1), 256, 0, stream>>>(g1);

    GP g2{};
    g2.A = hbf;
    g2.b[0] = GB{w2t + (size_t)l * DMODEL * DFF, b2 + l * DMODEL, fpart, 2};
    g2.M = SEQ; g2.N = DMODEL; g2.K = DFF; g2.kspl = 512; g2.wide = 0;
    k_gemm<64><<<dim3(DMODEL / 64, SEQ / 64, 4), 256, 0, stream>>>(g2);
  }
  k_final<<<SEQ / 4, 256, 0, stream>>>(xb, fpart, 4, Wout, bout, out);
}

// Round 10
// 532.323 us; speedup vs baseline: 1.7780x; 1.7780x over previous
//
#include <hip/hip_runtime.h>
#include <math.h>
#include <stdint.h>

#define SEQ 2048
#define DMODEL 512
#define NH 8
#define DHEAD 64
#define NL 4
#define DFF 2048

typedef __attribute__((ext_vector_type(8))) short short8;
typedef __attribute__((ext_vector_type(4))) float f32x4;

__device__ __forceinline__ short f2bf(float f) {
  unsigned u = __float_as_uint(f);
  u += 0x7fffu + ((u >> 16) & 1u);
  return (short)(u >> 16);
}
__device__ __forceinline__ float silu_f(float x) { return x / (1.f + __expf(-x)); }

// async global->LDS, 16B per lane; HW dest = wave-uniform base + lane*16
__device__ __forceinline__ void cp16(const void* g, void* l) {
  __builtin_amdgcn_global_load_lds(
      (const __attribute__((address_space(1))) unsigned*)(unsigned long long)(uintptr_t)g,
      (__attribute__((address_space(3))) unsigned*)(unsigned)(uintptr_t)l, 16, 0, 0);
}

// ---------------- merged prep: 7 transposes + sincos tables ----------------
struct TP { const float* src; short* dst; int rows, cols, base, lstride; };
struct TPs { TP t[7]; };
__global__ __launch_bounds__(256) void k_prep(TPs ts, float* __restrict__ sn, float* __restrict__ cs) {
  int bid = blockIdx.x;
  if (bid >= 13312) { // 256 blocks: fp64 sincos (65536 entries)
    int g = (bid - 13312) * 256 + threadIdx.x;
    int s = g >> 5, p = g & 31;
    double inv = pow(10000.0, -(double)p / 32.0);
    double a = (double)s * inv;
    float sv = (float)sin(a), cv = (float)cos(a);
    sn[s * DHEAD + 2 * p] = sv; sn[s * DHEAD + 2 * p + 1] = sv;
    cs[s * DHEAD + 2 * p] = cv; cs[s * DHEAD + 2 * p + 1] = cv;
    return;
  }
  int di = 6;
  while (di > 0 && bid < ts.t[di].base) --di;
  TP d = ts.t[di];
  int local = bid - d.base;
  int tx = d.cols >> 5, ty = d.rows >> 5;
  int tpz = tx * ty;
  int z = local / tpz, rem = local - z * tpz;
  int bx = (rem % tx) * 32, by = (rem / tx) * 32;
  const float* src = d.src + (size_t)z * d.rows * d.cols;
  short* dst = d.dst + (size_t)z * d.lstride;
  __shared__ float tile[32][33];
  int txi = threadIdx.x & 31, tyi = threadIdx.x >> 5; // 32 x 8
#pragma unroll
  for (int k = 0; k < 4; ++k)
    tile[tyi + k * 8][txi] = src[(size_t)(by + tyi + k * 8) * d.cols + bx + txi];
  __syncthreads();
#pragma unroll
  for (int k = 0; k < 4; ++k)
    dst[(size_t)(bx + tyi + k * 8) * d.rows + by + txi] = f2bf(tile[txi][tyi + k * 8]);
}

// ---------------- LayerNorm row(512): xnew = x + pos?(row0) + sum(parts); write-back; LN->bf16 ----------------
__global__ __launch_bounds__(256) void k_ln(const float* __restrict__ x, const float* __restrict__ parts, int np,
                                            const float* __restrict__ w, const float* __restrict__ b,
                                            short* __restrict__ o, float eps, float* __restrict__ xout,
                                            const float* __restrict__ pos) {
  int wid = threadIdx.x >> 6, lane = threadIdx.x & 63;
  int row = blockIdx.x * 4 + wid;
  size_t base = (size_t)row * DMODEL + lane * 8;
  float4 v0 = *(const float4*)(x + base);
  float4 v1 = *(const float4*)(x + base + 4);
  if (pos) { // reference broadcasts pos_emb[:B] => row 0 only
    float4 p0 = *(const float4*)(pos + lane * 8);
    float4 p1 = *(const float4*)(pos + lane * 8 + 4);
    v0.x += p0.x; v0.y += p0.y; v0.z += p0.z; v0.w += p0.w;
    v1.x += p1.x; v1.y += p1.y; v1.z += p1.z; v1.w += p1.w;
  }
  for (int p = 0; p < np; ++p) {
    const float* pp = parts + (size_t)p * SEQ * DMODEL;
    float4 a0 = *(const float4*)(pp + base);
    float4 a1 = *(const float4*)(pp + base + 4);
    v0.x += a0.x; v0.y += a0.y; v0.z += a0.z; v0.w += a0.w;
    v1.x += a1.x; v1.y += a1.y; v1.z += a1.z; v1.w += a1.w;
  }
  if (xout) {
    *(float4*)(xout + base) = v0;
    *(float4*)(xout + base + 4) = v1;
  }
  float sm = v0.x + v0.y + v0.z + v0.w + v1.x + v1.y + v1.z + v1.w;
  float sq = v0.x * v0.x + v0.y * v0.y + v0.z * v0.z + v0.w * v0.w +
             v1.x * v1.x + v1.y * v1.y + v1.z * v1.z + v1.w * v1.w;
#pragma unroll
  for (int m = 1; m < 64; m <<= 1) { sm += __shfl_xor(sm, m); sq += __shfl_xor(sq, m); }
  float mu = sm * (1.f / 512.f);
  float rstd = rsqrtf(sq * (1.f / 512.f) - mu * mu + eps);
  const float* wr = w + lane * 8; const float* br = b + lane * 8;
  float vals[8] = {v0.x, v0.y, v0.z, v0.w, v1.x, v1.y, v1.z, v1.w};
  short t[8] __attribute__((aligned(16)));
#pragma unroll
  for (int i = 0; i < 8; ++i) t[i] = f2bf((vals[i] - mu) * rstd * wr[i] + br[i]);
  *(int4*)(o + (size_t)row * DMODEL + lane * 8) = *(int4*)t;
}

// ---------------- bf16 MFMA GEMM, 64xBN tile, dbuf LDS via cp16, XOR-swizzled ----------------
// EPI: 0 fp32 store (DMODEL stride) | 1 silu->bf16 (N stride) | 2 fp32 PARTIAL at out+z*M*DMODEL (bias z==0)
//      4 bf16 transposed out[col*M+row] | 5 rope-q (*0.125)->bf16 | 6 rope-k ->bf16
// wide=1: N covers 4 slices of 512 cols; gb = b[n0>>9]; colO = col & 511.
struct GB { const short* Bt; const float* bias; void* out; int mode; };
struct GP {
  const short* A;
  const float* sn; const float* cs;
  GB b[4];
  int M, N, K, kspl, wide;
};

template <int BN>
__global__ __launch_bounds__(256) void k_gemm(GP ga) {
  constexpr int NBW = BN / 32;     // b-frags per wave (waves 2m x 2n)
  constexpr int BRND = BN / 32;    // cp16 rounds for B tile
  const int z = blockIdx.z;
  const int n0 = blockIdx.x * BN, m0 = blockIdx.y * 64;
  GB gb; int k0, klen;
  if (ga.kspl > 0) { gb = ga.b[0]; k0 = z * ga.kspl; klen = ga.kspl; }
  else { gb = ga.wide ? ga.b[n0 >> 9] : ga.b[z]; k0 = 0; klen = ga.K; }
  const int K = ga.K, N = ga.N, M = ga.M;
  const int tid = threadIdx.x;
  const int w = tid >> 6, lane = tid & 63, l16 = lane & 15, quad = lane >> 4;
  const int wm = (w & 1) * 32, wn = (w >> 1) * (BN / 2);
  const int nIter = klen >> 6;

  __shared__ __align__(16) short As[2][4096];      // [64][64] unpadded, chunk ^= (row&7)
  __shared__ __align__(16) short Bs[2][BN * 64];

  const short* Ab = ga.A + (size_t)m0 * K + k0;
  const short* Bb = gb.Bt + (size_t)n0 * K + k0;
  const int rsub = lane >> 3, cch = (lane & 7) ^ rsub;

  auto stage = [&](int buf, int it) {
#pragma unroll
    for (int c = 0; c < 2; ++c) {
      int seg = w + 4 * c;
      cp16(Ab + (size_t)(seg * 8 + rsub) * K + (it << 6) + cch * 8, &As[buf][seg * 512]);
    }
#pragma unroll
    for (int c = 0; c < BRND; ++c) {
      int seg = w + 4 * c;
      cp16(Bb + (size_t)(seg * 8 + rsub) * K + (it << 6) + cch * 8, &Bs[buf][seg * 512]);
    }
  };

  f32x4 acc[2][NBW];
#pragma unroll
  for (int a = 0; a < 2; ++a)
#pragma unroll
    for (int b = 0; b < NBW; ++b) acc[a][b] = {0.f, 0.f, 0.f, 0.f};

  stage(0, 0);
  for (int it = 0; it < nIter; ++it) {
    __syncthreads(); // vmcnt(0) drain: buf[it&1] ready
    if (it + 1 < nIter) stage((it + 1) & 1, it + 1);
    const short* as = As[it & 1];
    const short* bs = Bs[it & 1];
#pragma unroll
    for (int kki = 0; kki < 2; ++kki) {
      int ch = ((quad + 4 * kki) ^ (l16 & 7)) * 8;
      short8 af[2], bfv[NBW];
#pragma unroll
      for (int a = 0; a < 2; ++a) af[a] = *(const short8*)&as[(wm + a * 16 + l16) * 64 + ch];
#pragma unroll
      for (int b = 0; b < NBW; ++b) bfv[b] = *(const short8*)&bs[(wn + b * 16 + l16) * 64 + ch];
#pragma unroll
      for (int a = 0; a < 2; ++a)
#pragma unroll
        for (int b = 0; b < NBW; ++b)
          acc[a][b] = __builtin_amdgcn_mfma_f32_16x16x32_bf16(af[a], bfv[b], acc[a][b], 0, 0, 0);
    }
  }

  // epilogue: C/D layout col=lane&15, row=quad*4+reg (m89-verified)
  const int mode = gb.mode;
#pragma unroll
  for (int a = 0; a < 2; ++a) {
#pragma unroll
    for (int b = 0; b < NBW; ++b) {
      int row0 = m0 + wm + a * 16 + quad * 4;
      int col = n0 + wn + b * 16 + l16;
      int colO = ga.wide ? (col & 511) : col;
      float bi = (mode == 2 && z > 0) ? 0.f : gb.bias[colO];
      float vals[4];
#pragma unroll
      for (int r = 0; r < 4; ++r) vals[r] = acc[a][b][r] + bi;
      if (mode == 5 || mode == 6) {
        float sc = (mode == 5) ? 0.125f : 1.f;
        int d = colO & 63;
#pragma unroll
        for (int r = 0; r < 4; ++r) {
          int s = row0 + r;
          float vv = vals[r];
          float p = __shfl_xor(vv, 1); // partner col^1 lives in lane^1
          float rot = (colO & 1) ? p : -p;
          float o = (vv * ga.cs[s * 64 + d] + rot * ga.sn[s * 64 + d]) * sc;
          ((short*)gb.out)[(size_t)s * DMODEL + colO] = f2bf(o);
        }
      } else if (mode == 4) {
        short t4[4] __attribute__((aligned(8)));
#pragma unroll
        for (int r = 0; r < 4; ++r) t4[r] = f2bf(vals[r]);
        *(uint2*)&((short*)gb.out)[(size_t)colO * M + row0] = *(const uint2*)t4;
      } else if (mode == 0) {
#pragma unroll
        for (int r = 0; r < 4; ++r) ((float*)gb.out)[(size_t)(row0 + r) * DMODEL + colO] = vals[r];
      } else if (mode == 1) {
#pragma unroll
        for (int r = 0; r < 4; ++r) ((short*)gb.out)[(size_t)(row0 + r) * N + col] = f2bf(silu_f(vals[r]));
      } else { // mode 2: deterministic K-split partial
        float* po = (float*)gb.out + (size_t)z * M * DMODEL;
#pragma unroll
        for (int r = 0; r < 4; ++r) po[(size_t)(row0 + r) * DMODEL + colO] = vals[r];
      }
    }
  }
}

// ---------------- retention via MFMA: per block 64 i-rows x 1 head, j-parity split ----------------
// NOTE: no cross-block fences here — agent-scope __threadfence() on gfx950 flushes the
// whole per-XCD L2 (R9: 150us/dispatch). Separate k_retgate launch is ~3us. Keep it split.
__global__ __launch_bounds__(256) void k_attn(const short* __restrict__ qb, const short* __restrict__ kb,
                                              const short* __restrict__ vtb, float* __restrict__ r0,
                                              float* __restrict__ r1) {
  int x = blockIdx.x, hd = blockIdx.y, jc = blockIdx.z;
  int ib = jc ? (31 - x) : x; // balance: co-resident (x,0)+(x,1) ~ constant work
  int t = threadIdx.x;
  int w = t >> 6, lane = t & 63, l16 = lane & 15, quad = lane >> 4;
  __shared__ __align__(16) short smem[4 * 64 * 72];
  short* qs = smem;
  short* kt = smem + 4608;
  short* vt = smem + 9216;
  short* p  = smem + 13824;

  double stepd = (log(1.0 / 512.0) - log(1.0 / 32.0)) / 7.0;
  double gam = 1.0 - exp(log(1.0 / 32.0) + hd * stepd);
  float l2g = (float)(log(gam) * 1.4426950408889634);

  for (int c = t; c < 512; c += 256) {
    int r = c >> 3, d8 = (c & 7) * 8;
    *(short8*)&qs[r * 72 + d8] = *(const short8*)&qb[(size_t)(ib * 64 + r) * DMODEL + hd * DHEAD + d8];
  }
  f32x4 oacc[4];
#pragma unroll
  for (int b = 0; b < 4; ++b) oacc[b] = {0.f, 0.f, 0.f, 0.f};

  for (int jb = jc; jb <= ib; jb += 2) {
    __syncthreads();
    for (int c = t; c < 512; c += 256) {
      int r = c >> 3, d8 = (c & 7) * 8;
      *(short8*)&kt[r * 72 + d8] = *(const short8*)&kb[(size_t)(jb * 64 + r) * DMODEL + hd * DHEAD + d8];
      *(short8*)&vt[r * 72 + d8] = *(const short8*)&vtb[(size_t)(hd * DHEAD + r) * SEQ + jb * 64 + d8];
    }
    __syncthreads();
    f32x4 sacc[4];
#pragma unroll
    for (int b = 0; b < 4; ++b) sacc[b] = {0.f, 0.f, 0.f, 0.f};
#pragma unroll
    for (int kk = 0; kk < 64; kk += 32) {
      short8 af = *(const short8*)&qs[(w * 16 + l16) * 72 + kk + quad * 8];
#pragma unroll
      for (int b = 0; b < 4; ++b) {
        short8 bf_ = *(const short8*)&kt[(b * 16 + l16) * 72 + kk + quad * 8];
        sacc[b] = __builtin_amdgcn_mfma_f32_16x16x32_bf16(af, bf_, sacc[b], 0, 0, 0);
      }
    }
    int dtile = (ib - jb) * 64;
#pragma unroll
    for (int b = 0; b < 4; ++b) {
#pragma unroll
      for (int r = 0; r < 4; ++r) {
        int iloc = w * 16 + quad * 4 + r;
        int jloc = b * 16 + l16;
        int df = dtile + iloc - jloc;
        float dec = (df < 0) ? 0.f : exp2f(l2g * (float)df);
        p[iloc * 72 + jloc] = f2bf(sacc[b][r] * dec);
      }
    }
    __syncthreads();
#pragma unroll
    for (int kk = 0; kk < 64; kk += 32) {
      short8 af = *(const short8*)&vt[(w * 16 + l16) * 72 + kk + quad * 8];
#pragma unroll
      for (int b = 0; b < 4; ++b) {
        short8 bf_ = *(const short8*)&p[(b * 16 + l16) * 72 + kk + quad * 8];
        oacc[b] = __builtin_amdgcn_mfma_f32_16x16x32_bf16(af, bf_, oacc[b], 0, 0, 0);
      }
    }
  }
  __syncthreads();
  float* obuf = (float*)smem; // [64][68] fp32
#pragma unroll
  for (int b = 0; b < 4; ++b) {
#pragma unroll
    for (int r = 0; r < 4; ++r) {
      int d = w * 16 + quad * 4 + r;
      int i = b * 16 + l16;
      obuf[i * 68 + d] = oacc[b][r];
    }
  }
  __syncthreads();
  float* rp = jc ? r1 : r0;
  for (int c = t; c < 1024; c += 256) {
    int r = c >> 4, d4 = (c & 15) * 4;
    *(float4*)&rp[(size_t)(ib * 64 + r) * DMODEL + hd * DHEAD + d4] = *(const float4*)&obuf[r * 68 + d4];
  }
}

// ---------------- fused: combine partials + per-(s,h) normalize + silu gate -> bf16 ----------------
__global__ __launch_bounds__(256) void k_retgate(const float* __restrict__ r0, const float* __restrict__ r1,
                                                 const float* __restrict__ g, short* __restrict__ o) {
  int wid = threadIdx.x >> 6, lane = threadIdx.x & 63;
  int row = blockIdx.x * 4 + wid; // s*NH + h
  int s = row >> 3, hd = row & 7;
  size_t base = (size_t)s * DMODEL + hd * DHEAD + lane;
  float v = r0[base] + r1[base];
  float sm = v, sq = v * v;
#pragma unroll
  for (int m = 1; m < 64; m <<= 1) { sm += __shfl_xor(sm, m); sq += __shfl_xor(sq, m); }
  float mu = sm * (1.f / 64.f);
  float var = sq * (1.f / 64.f) - mu * mu;
  float rn = (v - mu) * rsqrtf(var + 1e-6f);
  o[base] = f2bf(silu_f(g[base]) * rn);
}

// ---------------- out = sigmoid((x + sum parts) @ Wout + bout), one wave per row ----------------
__global__ __launch_bounds__(256) void k_final(const float* __restrict__ x, const float* __restrict__ parts, int np,
                                               const float* __restrict__ w, const float* __restrict__ bo,
                                               float* __restrict__ o) {
  int wid = threadIdx.x >> 6, lane = threadIdx.x & 63;
  int row = blockIdx.x * 4 + wid;
  size_t base = (size_t)row * DMODEL + lane * 8;
  float4 a0 = *(const float4*)(x + base), a1 = *(const float4*)(x + base + 4);
  for (int p = 0; p < np; ++p) {
    const float* pp = parts + (size_t)p * SEQ * DMODEL;
    float4 b0 = *(const float4*)(pp + base);
    float4 b1 = *(const float4*)(pp + base + 4);
    a0.x += b0.x; a0.y += b0.y; a0.z += b0.z; a0.w += b0.w;
    a1.x += b1.x; a1.y += b1.y; a1.z += b1.z; a1.w += b1.w;
  }
  float4 w0 = *(const float4*)(w + lane * 8), w1 = *(const float4*)(w + lane * 8 + 4);
  float sm = a0.x * w0.x + a0.y * w0.y + a0.z * w0.z + a0.w * w0.w +
             a1.x * w1.x + a1.y * w1.y + a1.z * w1.z + a1.w * w1.w;
#pragma unroll
  for (int m = 1; m < 64; m <<= 1) sm += __shfl_xor(sm, m);
  if (lane == 0) o[row] = 1.f / (1.f + __expf(-(sm + bo[0])));
}

extern "C" void kernel_launch(void* const* d_in, const int* in_sizes, int n_in,
                              void* d_out, int out_size, void* d_ws, size_t ws_size,
                              hipStream_t stream) {
  const float* x_in = (const float*)d_in[0];
  const float* pos = (const float*)d_in[1];
  const float* Wq = (const float*)d_in[2];  const float* bq = (const float*)d_in[3];
  const float* Wk = (const float*)d_in[4];  const float* bk = (const float*)d_in[5];
  const float* Wv = (const float*)d_in[6];  const float* bv = (const float*)d_in[7];
  const float* Wg = (const float*)d_in[8];  const float* bg = (const float*)d_in[9];
  const float* Wo = (const float*)d_in[10]; const float* bo = (const float*)d_in[11];
  const float* ln1w = (const float*)d_in[12]; const float* ln1b = (const float*)d_in[13];
  const float* ln2w = (const float*)d_in[14]; const float* ln2b = (const float*)d_in[15];
  const float* W1 = (const float*)d_in[16]; const float* b1 = (const float*)d_in[17];
  const float* W2 = (const float*)d_in[18]; const float* b2 = (const float*)d_in[19];
  const float* Wout = (const float*)d_in[20]; const float* bout = (const float*)d_in[21];
  float* out = (float*)d_out;

  char* ws = (char*)d_ws;
  size_t off = 0;
  auto alloc = [&](size_t bytes) -> void* {
    void* p = ws + off;
    off += (bytes + 255) & ~(size_t)255;
    return p;
  };
  const size_t DD = (size_t)DMODEL * DMODEL;
  const size_t SD = (size_t)SEQ * DMODEL;
  short* wqkvg = (short*)alloc((size_t)NL * 4 * DD * 2); // [l][slice q,k,v,g][n][k]
  short* wot = (short*)alloc((size_t)NL * DD * 2);
  short* w1t = (short*)alloc((size_t)NL * DMODEL * DFF * 2);
  short* w2t = (short*)alloc((size_t)NL * DMODEL * DFF * 2);
  float* xb = (float*)alloc(SD * 4);
  short* ybf = (short*)alloc(SD * 2);
  float* graw = (float*)alloc(SD * 4);
  short* qb = (short*)alloc(SD * 2);
  short* kb = (short*)alloc(SD * 2);
  short* vtb = (short*)alloc(SD * 2);
  float* ret0 = (float*)alloc(SD * 4);
  float* ret1 = (float*)alloc(SD * 4);
  short* grb = (short*)alloc(SD * 2);
  short* zbf = (short*)alloc(SD * 2);
  short* hbf = (short*)alloc((size_t)SEQ * DFF * 2);
  float* sint = (float*)alloc((size_t)SEQ * DHEAD * 4);
  float* cost = (float*)alloc((size_t)SEQ * DHEAD * 4);
  float* wpart = (float*)alloc(2 * SD * 4);  // Wo K-split partials
  float* fpart = (float*)alloc(4 * SD * 4);  // FFN2 K-split partials

  TPs tp;
  tp.t[0] = TP{Wq, wqkvg + 0 * DD, DMODEL, DMODEL, 0, (int)(4 * DD)};
  tp.t[1] = TP{Wk, wqkvg + 1 * DD, DMODEL, DMODEL, 1024, (int)(4 * DD)};
  tp.t[2] = TP{Wv, wqkvg + 2 * DD, DMODEL, DMODEL, 2048, (int)(4 * DD)};
  tp.t[3] = TP{Wg, wqkvg + 3 * DD, DMODEL, DMODEL, 3072, (int)(4 * DD)};
  tp.t[4] = TP{Wo, wot, DMODEL, DMODEL, 4096, (int)DD};
  tp.t[5] = TP{W1, w1t, DMODEL, DFF, 5120, DMODEL * DFF};
  tp.t[6] = TP{W2, w2t, DFF, DMODEL, 9216, DMODEL * DFF};
  k_prep<<<13568, 256, 0, stream>>>(tp, sint, cost);

  for (int l = 0; l < NL; ++l) {
    // LN1: l==0 reads x_in + pos(row0), writes xb; l>0 reduces FFN2 partials into xb
    k_ln<<<SEQ / 4, 256, 0, stream>>>(l == 0 ? x_in : xb, fpart, l == 0 ? 0 : 4,
                                      ln1w + l * DMODEL, ln1b + l * DMODEL, ybf, 1e-5f,
                                      xb, l == 0 ? pos : nullptr);

    // merged qkvg: one GEMM, N=2048 (4 slices of 512), 512 blocks
    GP gq{};
    gq.A = ybf; gq.sn = sint; gq.cs = cost;
    gq.b[0] = GB{wqkvg + (size_t)l * 4 * DD, bq + l * DMODEL, qb, 5};
    gq.b[1] = GB{wqkvg + (size_t)l * 4 * DD, bk + l * DMODEL, kb, 6};
    gq.b[2] = GB{wqkvg + (size_t)l * 4 * DD, bv + l * DMODEL, vtb, 4};
    gq.b[3] = GB{wqkvg + (size_t)l * 4 * DD, bg + l * DMODEL, graw, 0};
    gq.M = SEQ; gq.N = 4 * DMODEL; gq.K = DMODEL; gq.kspl = 0; gq.wide = 1;
    k_gemm<128><<<dim3(16, SEQ / 64, 1), 256, 0, stream>>>(gq);

    k_attn<<<dim3(32, NH, 2), 256, 0, stream>>>(qb, kb, vtb, ret0, ret1);
    k_retgate<<<SEQ * NH / 4, 256, 0, stream>>>(ret0, ret1, graw, grb);

    GP gw{};
    gw.A = grb;
    gw.b[0] = GB{wot + l * DD, bo + l * DMODEL, wpart, 2};
    gw.M = SEQ; gw.N = DMODEL; gw.K = DMODEL; gw.kspl = 256; gw.wide = 0;
    k_gemm<64><<<dim3(DMODEL / 64, SEQ / 64, 2), 256, 0, stream>>>(gw);

    // LN2 + reduce of Wo partials into xb
    k_ln<<<SEQ / 4, 256, 0, stream>>>(xb, wpart, 2,
                                      ln2w + l * DMODEL, ln2b + l * DMODEL, zbf, 1e-5f, xb, nullptr);

    GP g1{};
    g1.A = zbf;
    g1.b[0] = GB{w1t + (size_t)l * DMODEL * DFF, b1 + l * DFF, hbf, 1};
    g1.M = SEQ; g1.N = DFF; g1.K = DMODEL; g1.kspl = 0; g1.wide = 0;
    k_gemm<128><<<dim3(DFF / 128, SEQ / 64, 1), 256, 0, stream>>>(g1);

    GP g2{};
    g2.A = hbf;
    g2.b[0] = GB{w2t + (size_t)l * DMODEL * DFF, b2 + l * DMODEL, fpart, 2};
    g2.M = SEQ; g2.N = DMODEL; g2.K = DFF; g2.kspl = 512; g2.wide = 0;
    k_gemm<64><<<dim3(DMODEL / 64, SEQ / 64, 4), 256, 0, stream>>>(g2);
  }
  k_final<<<SEQ / 4, 256, 0, stream>>>(xb, fpart, 4, Wout, bout, out);
}

// Round 11
// 500.164 us; speedup vs baseline: 1.8923x; 1.0643x over previous
//
#include <hip/hip_runtime.h>
#include <math.h>
#include <stdint.h>

#define SEQ 2048
#define DMODEL 512
#define NH 8
#define DHEAD 64
#define NL 4
#define DFF 2048

typedef __attribute__((ext_vector_type(8))) short short8;
typedef __attribute__((ext_vector_type(4))) float f32x4;
typedef __attribute__((ext_vector_type(16))) float f32x16;

__device__ __forceinline__ short f2bf(float f) {
  unsigned u = __float_as_uint(f);
  u += 0x7fffu + ((u >> 16) & 1u);
  return (short)(u >> 16);
}
__device__ __forceinline__ float silu_f(float x) { return x / (1.f + __expf(-x)); }

// async global->LDS, 16B per lane; HW dest = wave-uniform base + lane*16
__device__ __forceinline__ void cp16(const void* g, void* l) {
  __builtin_amdgcn_global_load_lds(
      (const __attribute__((address_space(1))) unsigned*)(unsigned long long)(uintptr_t)g,
      (__attribute__((address_space(3))) unsigned*)(unsigned)(uintptr_t)l, 16, 0, 0);
}

// ---------------- merged prep: 7 transposes + sincos tables ----------------
struct TP { const float* src; short* dst; int rows, cols, base, lstride; };
struct TPs { TP t[7]; };
__global__ __launch_bounds__(256) void k_prep(TPs ts, float* __restrict__ sn, float* __restrict__ cs) {
  int bid = blockIdx.x;
  if (bid >= 13312) { // 256 blocks: fp64 sincos (65536 entries)
    int g = (bid - 13312) * 256 + threadIdx.x;
    int s = g >> 5, p = g & 31;
    double inv = pow(10000.0, -(double)p / 32.0);
    double a = (double)s * inv;
    float sv = (float)sin(a), cv = (float)cos(a);
    sn[s * DHEAD + 2 * p] = sv; sn[s * DHEAD + 2 * p + 1] = sv;
    cs[s * DHEAD + 2 * p] = cv; cs[s * DHEAD + 2 * p + 1] = cv;
    return;
  }
  int di = 6;
  while (di > 0 && bid < ts.t[di].base) --di;
  TP d = ts.t[di];
  int local = bid - d.base;
  int tx = d.cols >> 5, ty = d.rows >> 5;
  int tpz = tx * ty;
  int z = local / tpz, rem = local - z * tpz;
  int bx = (rem % tx) * 32, by = (rem / tx) * 32;
  const float* src = d.src + (size_t)z * d.rows * d.cols;
  short* dst = d.dst + (size_t)z * d.lstride;
  __shared__ float tile[32][33];
  int txi = threadIdx.x & 31, tyi = threadIdx.x >> 5; // 32 x 8
#pragma unroll
  for (int k = 0; k < 4; ++k)
    tile[tyi + k * 8][txi] = src[(size_t)(by + tyi + k * 8) * d.cols + bx + txi];
  __syncthreads();
#pragma unroll
  for (int k = 0; k < 4; ++k)
    dst[(size_t)(bx + tyi + k * 8) * d.rows + by + txi] = f2bf(tile[txi][tyi + k * 8]);
}

// ---------------- LayerNorm row(512): xnew = x + pos?(row0) + sum(parts); write-back; LN->bf16 ----------------
__global__ __launch_bounds__(256) void k_ln(const float* __restrict__ x, const float* __restrict__ parts, int np,
                                            const float* __restrict__ w, const float* __restrict__ b,
                                            short* __restrict__ o, float eps, float* __restrict__ xout,
                                            const float* __restrict__ pos) {
  int wid = threadIdx.x >> 6, lane = threadIdx.x & 63;
  int row = blockIdx.x * 4 + wid;
  size_t base = (size_t)row * DMODEL + lane * 8;
  float4 v0 = *(const float4*)(x + base);
  float4 v1 = *(const float4*)(x + base + 4);
  if (pos) { // reference broadcasts pos_emb[:B] => row 0 only
    float4 p0 = *(const float4*)(pos + lane * 8);
    float4 p1 = *(const float4*)(pos + lane * 8 + 4);
    v0.x += p0.x; v0.y += p0.y; v0.z += p0.z; v0.w += p0.w;
    v1.x += p1.x; v1.y += p1.y; v1.z += p1.z; v1.w += p1.w;
  }
  for (int p = 0; p < np; ++p) {
    const float* pp = parts + (size_t)p * SEQ * DMODEL;
    float4 a0 = *(const float4*)(pp + base);
    float4 a1 = *(const float4*)(pp + base + 4);
    v0.x += a0.x; v0.y += a0.y; v0.z += a0.z; v0.w += a0.w;
    v1.x += a1.x; v1.y += a1.y; v1.z += a1.z; v1.w += a1.w;
  }
  if (xout) {
    *(float4*)(xout + base) = v0;
    *(float4*)(xout + base + 4) = v1;
  }
  float sm = v0.x + v0.y + v0.z + v0.w + v1.x + v1.y + v1.z + v1.w;
  float sq = v0.x * v0.x + v0.y * v0.y + v0.z * v0.z + v0.w * v0.w +
             v1.x * v1.x + v1.y * v1.y + v1.z * v1.z + v1.w * v1.w;
#pragma unroll
  for (int m = 1; m < 64; m <<= 1) { sm += __shfl_xor(sm, m); sq += __shfl_xor(sq, m); }
  float mu = sm * (1.f / 512.f);
  float rstd = rsqrtf(sq * (1.f / 512.f) - mu * mu + eps);
  const float* wr = w + lane * 8; const float* br = b + lane * 8;
  float vals[8] = {v0.x, v0.y, v0.z, v0.w, v1.x, v1.y, v1.z, v1.w};
  short t[8] __attribute__((aligned(16)));
#pragma unroll
  for (int i = 0; i < 8; ++i) t[i] = f2bf((vals[i] - mu) * rstd * wr[i] + br[i]);
  *(int4*)(o + (size_t)row * DMODEL + lane * 8) = *(int4*)t;
}

// ---------------- bf16 MFMA GEMM, 64xBN tile, 32x32x16 MFMA, dbuf LDS via cp16, XOR-swizzled ----------------
// waves 2x2: wave tile 32 x (BN/2). A/B frag: [row=lane&31][k=(lane>>5)*8+j].
// C/D (m74/m101-verified): col=lane&31, row=(reg&3)+8*(reg>>2)+4*(lane>>5).
// EPI: 0 fp32 store (DMODEL stride) | 1 silu->bf16 (N stride) | 2 fp32 PARTIAL at out+z*M*DMODEL (bias z==0)
//      4 bf16 transposed out[col*M+row] | 5 rope-q (*0.125)->bf16 | 6 rope-k ->bf16
// wide=1: N covers 4 slices of 512 cols; gb = b[n0>>9]; colO = col & 511.
struct GB { const short* Bt; const float* bias; void* out; int mode; };
struct GP {
  const short* A;
  const float* sn; const float* cs;
  GB b[4];
  int M, N, K, kspl, wide;
};

template <int BN>
__global__ __launch_bounds__(256) void k_gemm(GP ga) {
  constexpr int NB = BN / 64;      // 32x32 b-frags per wave
  constexpr int BRND = BN / 32;    // cp16 rounds for B tile
  const int z = blockIdx.z;
  const int n0 = blockIdx.x * BN, m0 = blockIdx.y * 64;
  GB gb; int k0, klen;
  if (ga.kspl > 0) { gb = ga.b[0]; k0 = z * ga.kspl; klen = ga.kspl; }
  else { gb = ga.wide ? ga.b[n0 >> 9] : ga.b[z]; k0 = 0; klen = ga.K; }
  const int K = ga.K, N = ga.N, M = ga.M;
  const int tid = threadIdx.x;
  const int w = tid >> 6, lane = tid & 63;
  const int l32 = lane & 31, half = lane >> 5;
  const int wm = (w & 1) * 32, wn = (w >> 1) * (BN / 2);
  const int nIter = klen >> 6;

  __shared__ __align__(16) short As[2][4096];      // [64][64] unpadded, chunk ^= (row&7)
  __shared__ __align__(16) short Bs[2][BN * 64];

  const short* Ab = ga.A + (size_t)m0 * K + k0;
  const short* Bb = gb.Bt + (size_t)n0 * K + k0;
  const int rsub = lane >> 3, cch = (lane & 7) ^ rsub;

  auto stage = [&](int buf, int it) {
#pragma unroll
    for (int c = 0; c < 2; ++c) {
      int seg = w + 4 * c;
      cp16(Ab + (size_t)(seg * 8 + rsub) * K + (it << 6) + cch * 8, &As[buf][seg * 512]);
    }
#pragma unroll
    for (int c = 0; c < BRND; ++c) {
      int seg = w + 4 * c;
      cp16(Bb + (size_t)(seg * 8 + rsub) * K + (it << 6) + cch * 8, &Bs[buf][seg * 512]);
    }
  };

  f32x16 acc[NB] = {};

  stage(0, 0);
  for (int it = 0; it < nIter; ++it) {
    __syncthreads(); // vmcnt(0) drain: buf[it&1] ready
    if (it + 1 < nIter) stage((it + 1) & 1, it + 1);
    const short* as = As[it & 1];
    const short* bs = Bs[it & 1];
#pragma unroll
    for (int s = 0; s < 4; ++s) { // K=16 slices of the 64-K tile
      int slot = ((2 * s + half) ^ (l32 & 7)) * 8;
      short8 af = *(const short8*)&as[(wm + l32) * 64 + slot];
#pragma unroll
      for (int b = 0; b < NB; ++b) {
        short8 bf_ = *(const short8*)&bs[(wn + b * 32 + l32) * 64 + slot];
        acc[b] = __builtin_amdgcn_mfma_f32_32x32x16_bf16(af, bf_, acc[b], 0, 0, 0);
      }
    }
  }

  // epilogue
  const int mode = gb.mode;
#pragma unroll
  for (int b = 0; b < NB; ++b) {
    int col = n0 + wn + b * 32 + l32;
    int colO = ga.wide ? (col & 511) : col;
    float bi = (mode == 2 && z > 0) ? 0.f : gb.bias[colO];
    if (mode == 5 || mode == 6) {
      float sc = (mode == 5) ? 0.125f : 1.f;
      int d = colO & 63;
#pragma unroll
      for (int r = 0; r < 16; ++r) {
        int row = m0 + wm + (r & 3) + 8 * (r >> 2) + 4 * half;
        float vv = acc[b][r] + bi;
        float p = __shfl_xor(vv, 1); // partner col^1 lives in lane^1 (same row: row dep on half only)
        float rot = (colO & 1) ? p : -p;
        float o = (vv * ga.cs[row * 64 + d] + rot * ga.sn[row * 64 + d]) * sc;
        ((short*)gb.out)[(size_t)row * DMODEL + colO] = f2bf(o);
      }
    } else if (mode == 4) {
#pragma unroll
      for (int g = 0; g < 4; ++g) {
        short t4[4] __attribute__((aligned(8)));
#pragma unroll
        for (int j = 0; j < 4; ++j) t4[j] = f2bf(acc[b][g * 4 + j] + bi);
        int row0 = m0 + wm + 8 * g + 4 * half;
        *(uint2*)&((short*)gb.out)[(size_t)colO * M + row0] = *(const uint2*)t4;
      }
    } else if (mode == 0) {
#pragma unroll
      for (int r = 0; r < 16; ++r) {
        int row = m0 + wm + (r & 3) + 8 * (r >> 2) + 4 * half;
        ((float*)gb.out)[(size_t)row * DMODEL + colO] = acc[b][r] + bi;
      }
    } else if (mode == 1) {
#pragma unroll
      for (int r = 0; r < 16; ++r) {
        int row = m0 + wm + (r & 3) + 8 * (r >> 2) + 4 * half;
        ((short*)gb.out)[(size_t)row * N + col] = f2bf(silu_f(acc[b][r] + bi));
      }
    } else { // mode 2: deterministic K-split partial
      float* po = (float*)gb.out + (size_t)z * M * DMODEL;
#pragma unroll
      for (int r = 0; r < 16; ++r) {
        int row = m0 + wm + (r & 3) + 8 * (r >> 2) + 4 * half;
        po[(size_t)row * DMODEL + colO] = acc[b][r] + bi;
      }
    }
  }
}

// ---------------- retention via MFMA: per block 64 i-rows x 1 head, j-parity split ----------------
// NOTE: no cross-block fences — agent-scope __threadfence() on gfx950 flushes the per-XCD L2
// (R9: 150us/dispatch). Separate k_retgate launch is ~3us. Keep it split.
__global__ __launch_bounds__(256) void k_attn(const short* __restrict__ qb, const short* __restrict__ kb,
                                              const short* __restrict__ vtb, float* __restrict__ r0,
                                              float* __restrict__ r1) {
  int x = blockIdx.x, hd = blockIdx.y, jc = blockIdx.z;
  int ib = jc ? (31 - x) : x; // balance: co-resident (x,0)+(x,1) ~ constant work
  int t = threadIdx.x;
  int w = t >> 6, lane = t & 63, l16 = lane & 15, quad = lane >> 4;
  __shared__ __align__(16) short smem[4 * 64 * 72];
  short* qs = smem;
  short* kt = smem + 4608;
  short* vt = smem + 9216;
  short* p  = smem + 13824;

  double stepd = (log(1.0 / 512.0) - log(1.0 / 32.0)) / 7.0;
  double gam = 1.0 - exp(log(1.0 / 32.0) + hd * stepd);
  float l2g = (float)(log(gam) * 1.4426950408889634);

  for (int c = t; c < 512; c += 256) {
    int r = c >> 3, d8 = (c & 7) * 8;
    *(short8*)&qs[r * 72 + d8] = *(const short8*)&qb[(size_t)(ib * 64 + r) * DMODEL + hd * DHEAD + d8];
  }
  f32x4 oacc[4];
#pragma unroll
  for (int b = 0; b < 4; ++b) oacc[b] = {0.f, 0.f, 0.f, 0.f};

  for (int jb = jc; jb <= ib; jb += 2) {
    __syncthreads();
    for (int c = t; c < 512; c += 256) {
      int r = c >> 3, d8 = (c & 7) * 8;
      *(short8*)&kt[r * 72 + d8] = *(const short8*)&kb[(size_t)(jb * 64 + r) * DMODEL + hd * DHEAD + d8];
      *(short8*)&vt[r * 72 + d8] = *(const short8*)&vtb[(size_t)(hd * DHEAD + r) * SEQ + jb * 64 + d8];
    }
    __syncthreads();
    f32x4 sacc[4];
#pragma unroll
    for (int b = 0; b < 4; ++b) sacc[b] = {0.f, 0.f, 0.f, 0.f};
#pragma unroll
    for (int kk = 0; kk < 64; kk += 32) {
      short8 af = *(const short8*)&qs[(w * 16 + l16) * 72 + kk + quad * 8];
#pragma unroll
      for (int b = 0; b < 4; ++b) {
        short8 bf_ = *(const short8*)&kt[(b * 16 + l16) * 72 + kk + quad * 8];
        sacc[b] = __builtin_amdgcn_mfma_f32_16x16x32_bf16(af, bf_, sacc[b], 0, 0, 0);
      }
    }
    int dtile = (ib - jb) * 64;
#pragma unroll
    for (int b = 0; b < 4; ++b) {
#pragma unroll
      for (int r = 0; r < 4; ++r) {
        int iloc = w * 16 + quad * 4 + r;
        int jloc = b * 16 + l16;
        int df = dtile + iloc - jloc;
        float dec = (df < 0) ? 0.f : exp2f(l2g * (float)df);
        p[iloc * 72 + jloc] = f2bf(sacc[b][r] * dec);
      }
    }
    __syncthreads();
#pragma unroll
    for (int kk = 0; kk < 64; kk += 32) {
      short8 af = *(const short8*)&vt[(w * 16 + l16) * 72 + kk + quad * 8];
#pragma unroll
      for (int b = 0; b < 4; ++b) {
        short8 bf_ = *(const short8*)&p[(b * 16 + l16) * 72 + kk + quad * 8];
        oacc[b] = __builtin_amdgcn_mfma_f32_16x16x32_bf16(af, bf_, oacc[b], 0, 0, 0);
      }
    }
  }
  __syncthreads();
  float* obuf = (float*)smem; // [64][68] fp32
#pragma unroll
  for (int b = 0; b < 4; ++b) {
#pragma unroll
    for (int r = 0; r < 4; ++r) {
      int d = w * 16 + quad * 4 + r;
      int i = b * 16 + l16;
      obuf[i * 68 + d] = oacc[b][r];
    }
  }
  __syncthreads();
  float* rp = jc ? r1 : r0;
  for (int c = t; c < 1024; c += 256) {
    int r = c >> 4, d4 = (c & 15) * 4;
    *(float4*)&rp[(size_t)(ib * 64 + r) * DMODEL + hd * DHEAD + d4] = *(const float4*)&obuf[r * 68 + d4];
  }
}

// ---------------- fused: combine partials + per-(s,h) normalize + silu gate -> bf16 ----------------
__global__ __launch_bounds__(256) void k_retgate(const float* __restrict__ r0, const float* __restrict__ r1,
                                                 const float* __restrict__ g, short* __restrict__ o) {
  int wid = threadIdx.x >> 6, lane = threadIdx.x & 63;
  int row = blockIdx.x * 4 + wid; // s*NH + h
  int s = row >> 3, hd = row & 7;
  size_t base = (size_t)s * DMODEL + hd * DHEAD + lane;
  float v = r0[base] + r1[base];
  float sm = v, sq = v * v;
#pragma unroll
  for (int m = 1; m < 64; m <<= 1) { sm += __shfl_xor(sm, m); sq += __shfl_xor(sq, m); }
  float mu = sm * (1.f / 64.f);
  float var = sq * (1.f / 64.f) - mu * mu;
  float rn = (v - mu) * rsqrtf(var + 1e-6f);
  o[base] = f2bf(silu_f(g[base]) * rn);
}

// ---------------- out = sigmoid((x + sum parts) @ Wout + bout), one wave per row ----------------
__global__ __launch_bounds__(256) void k_final(const float* __restrict__ x, const float* __restrict__ parts, int np,
                                               const float* __restrict__ w, const float* __restrict__ bo,
                                               float* __restrict__ o) {
  int wid = threadIdx.x >> 6, lane = threadIdx.x & 63;
  int row = blockIdx.x * 4 + wid;
  size_t base = (size_t)row * DMODEL + lane * 8;
  float4 a0 = *(const float4*)(x + base), a1 = *(const float4*)(x + base + 4);
  for (int p = 0; p < np; ++p) {
    const float* pp = parts + (size_t)p * SEQ * DMODEL;
    float4 b0 = *(const float4*)(pp + base);
    float4 b1 = *(const float4*)(pp + base + 4);
    a0.x += b0.x; a0.y += b0.y; a0.z += b0.z; a0.w += b0.w;
    a1.x += b1.x; a1.y += b1.y; a1.z += b1.z; a1.w += b1.w;
  }
  float4 w0 = *(const float4*)(w + lane * 8), w1 = *(const float4*)(w + lane * 8 + 4);
  float sm = a0.x * w0.x + a0.y * w0.y + a0.z * w0.z + a0.w * w0.w +
             a1.x * w1.x + a1.y * w1.y + a1.z * w1.z + a1.w * w1.w;
#pragma unroll
  for (int m = 1; m < 64; m <<= 1) sm += __shfl_xor(sm, m);
  if (lane == 0) o[row] = 1.f / (1.f + __expf(-(sm + bo[0])));
}

extern "C" void kernel_launch(void* const* d_in, const int* in_sizes, int n_in,
                              void* d_out, int out_size, void* d_ws, size_t ws_size,
                              hipStream_t stream) {
  const float* x_in = (const float*)d_in[0];
  const float* pos = (const float*)d_in[1];
  const float* Wq = (const float*)d_in[2];  const float* bq = (const float*)d_in[3];
  const float* Wk = (const float*)d_in[4];  const float* bk = (const float*)d_in[5];
  const float* Wv = (const float*)d_in[6];  const float* bv = (const float*)d_in[7];
  const float* Wg = (const float*)d_in[8];  const float* bg = (const float*)d_in[9];
  const float* Wo = (const float*)d_in[10]; const float* bo = (const float*)d_in[11];
  const float* ln1w = (const float*)d_in[12]; const float* ln1b = (const float*)d_in[13];
  const float* ln2w = (const float*)d_in[14]; const float* ln2b = (const float*)d_in[15];
  const float* W1 = (const float*)d_in[16]; const float* b1 = (const float*)d_in[17];
  const float* W2 = (const float*)d_in[18]; const float* b2 = (const float*)d_in[19];
  const float* Wout = (const float*)d_in[20]; const float* bout = (const float*)d_in[21];
  float* out = (float*)d_out;

  char* ws = (char*)d_ws;
  size_t off = 0;
  auto alloc = [&](size_t bytes) -> void* {
    void* p = ws + off;
    off += (bytes + 255) & ~(size_t)255;
    return p;
  };
  const size_t DD = (size_t)DMODEL * DMODEL;
  const size_t SD = (size_t)SEQ * DMODEL;
  short* wqkvg = (short*)alloc((size_t)NL * 4 * DD * 2); // [l][slice q,k,v,g][n][k]
  short* wot = (short*)alloc((size_t)NL * DD * 2);
  short* w1t = (short*)alloc((size_t)NL * DMODEL * DFF * 2);
  short* w2t = (short*)alloc((size_t)NL * DMODEL * DFF * 2);
  float* xb = (float*)alloc(SD * 4);
  short* ybf = (short*)alloc(SD * 2);
  float* graw = (float*)alloc(SD * 4);
  short* qb = (short*)alloc(SD * 2);
  short* kb = (short*)alloc(SD * 2);
  short* vtb = (short*)alloc(SD * 2);
  float* ret0 = (float*)alloc(SD * 4);
  float* ret1 = (float*)alloc(SD * 4);
  short* grb = (short*)alloc(SD * 2);
  short* zbf = (short*)alloc(SD * 2);
  short* hbf = (short*)alloc((size_t)SEQ * DFF * 2);
  float* sint = (float*)alloc((size_t)SEQ * DHEAD * 4);
  float* cost = (float*)alloc((size_t)SEQ * DHEAD * 4);
  float* wpart = (float*)alloc(2 * SD * 4);  // Wo K-split partials
  float* fpart = (float*)alloc(2 * SD * 4);  // FFN2 K-split partials (z=2 now)

  TPs tp;
  tp.t[0] = TP{Wq, wqkvg + 0 * DD, DMODEL, DMODEL, 0, (int)(4 * DD)};
  tp.t[1] = TP{Wk, wqkvg + 1 * DD, DMODEL, DMODEL, 1024, (int)(4 * DD)};
  tp.t[2] = TP{Wv, wqkvg + 2 * DD, DMODEL, DMODEL, 2048, (int)(4 * DD)};
  tp.t[3] = TP{Wg, wqkvg + 3 * DD, DMODEL, DMODEL, 3072, (int)(4 * DD)};
  tp.t[4] = TP{Wo, wot, DMODEL, DMODEL, 4096, (int)DD};
  tp.t[5] = TP{W1, w1t, DMODEL, DFF, 5120, DMODEL * DFF};
  tp.t[6] = TP{W2, w2t, DFF, DMODEL, 9216, DMODEL * DFF};
  k_prep<<<13568, 256, 0, stream>>>(tp, sint, cost);

  for (int l = 0; l < NL; ++l) {
    // LN1: l==0 reads x_in + pos(row0), writes xb; l>0 reduces FFN2 partials into xb
    k_ln<<<SEQ / 4, 256, 0, stream>>>(l == 0 ? x_in : xb, fpart, l == 0 ? 0 : 2,
                                      ln1w + l * DMODEL, ln1b + l * DMODEL, ybf, 1e-5f,
                                      xb, l == 0 ? pos : nullptr);

    // merged qkvg: one GEMM, N=2048 (4 slices of 512), 512 blocks
    GP gq{};
    gq.A = ybf; gq.sn = sint; gq.cs = cost;
    gq.b[0] = GB{wqkvg + (size_t)l * 4 * DD, bq + l * DMODEL, qb, 5};
    gq.b[1] = GB{wqkvg + (size_t)l * 4 * DD, bk + l * DMODEL, kb, 6};
    gq.b[2] = GB{wqkvg + (size_t)l * 4 * DD, bv + l * DMODEL, vtb, 4};
    gq.b[3] = GB{wqkvg + (size_t)l * 4 * DD, bg + l * DMODEL, graw, 0};
    gq.M = SEQ; gq.N = 4 * DMODEL; gq.K = DMODEL; gq.kspl = 0; gq.wide = 1;
    k_gemm<128><<<dim3(16, SEQ / 64, 1), 256, 0, stream>>>(gq);

    k_attn<<<dim3(32, NH, 2), 256, 0, stream>>>(qb, kb, vtb, ret0, ret1);
    k_retgate<<<SEQ * NH / 4, 256, 0, stream>>>(ret0, ret1, graw, grb);

    GP gw{};
    gw.A = grb;
    gw.b[0] = GB{wot + l * DD, bo + l * DMODEL, wpart, 2};
    gw.M = SEQ; gw.N = DMODEL; gw.K = DMODEL; gw.kspl = 256; gw.wide = 0;
    k_gemm<64><<<dim3(DMODEL / 64, SEQ / 64, 2), 256, 0, stream>>>(gw);

    // LN2 + reduce of Wo partials into xb
    k_ln<<<SEQ / 4, 256, 0, stream>>>(xb, wpart, 2,
                                      ln2w + l * DMODEL, ln2b + l * DMODEL, zbf, 1e-5f, xb, nullptr);

    GP g1{};
    g1.A = zbf;
    g1.b[0] = GB{w1t + (size_t)l * DMODEL * DFF, b1 + l * DFF, hbf, 1};
    g1.M = SEQ; g1.N = DFF; g1.K = DMODEL; g1.kspl = 0; g1.wide = 0;
    k_gemm<128><<<dim3(DFF / 128, SEQ / 64, 1), 256, 0, stream>>>(g1);

    GP g2{};
    g2.A = hbf;
    g2.b[0] = GB{w2t + (size_t)l * DMODEL * DFF, b2 + l * DMODEL, fpart, 2};
    g2.M = SEQ; g2.N = DMODEL; g2.K = DFF; g2.kspl = 1024; g2.wide = 0;
    k_gemm<64><<<dim3(DMODEL / 64, SEQ / 64, 2), 256, 0, stream>>>(g2);
  }
  k_final<<<SEQ / 4, 256, 0, stream>>>(xb, fpart, 2, Wout, bout, out);
}